// Round 1
// baseline (651.041 us; speedup 1.0000x reference)
//
#include <hip/hip_runtime.h>

// ---------------------------------------------------------------------------
// Kernel A: i_x[t,b,n] = sum_k x[t,b,k] * w_in[k,n]
// Plain fp32 vector GEMM: M = T*B = 128000, K = 256, N = 256.
// Tile 128x128, 256 threads, 8x8 micro-tile per thread, BK=32.
// ---------------------------------------------------------------------------
__global__ __launch_bounds__(256) void gemm_xw(const float* __restrict__ X,
                                               const float* __restrict__ W,
                                               float* __restrict__ Y,
                                               int M) {
    __shared__ float As[32][132];  // transposed A tile, padded (132 keeps 16B align + debanks writes)
    __shared__ float Bs[32][128];

    const int tid = threadIdx.x;
    const int mb = blockIdx.x >> 1;
    const int nb = blockIdx.x & 1;
    const int m0 = mb << 7;
    const int n0 = nb << 7;
    const int tr = (tid >> 4) << 3;
    const int tc = (tid & 15) << 3;

    float acc[8][8];
#pragma unroll
    for (int i = 0; i < 8; ++i)
#pragma unroll
        for (int j = 0; j < 8; ++j) acc[i][j] = 0.f;

    for (int kb = 0; kb < 256; kb += 32) {
#pragma unroll
        for (int i = 0; i < 4; ++i) {
            int f = tid + (i << 8);
            // A: 128 rows x 32 k ; thread reads float4, writes transposed scalars
            int row = f >> 3, kq = f & 7;
            float4 a = *(const float4*)(X + (size_t)(m0 + row) * 256 + kb + (kq << 2));
            As[(kq << 2) + 0][row] = a.x;
            As[(kq << 2) + 1][row] = a.y;
            As[(kq << 2) + 2][row] = a.z;
            As[(kq << 2) + 3][row] = a.w;
            // B: 32 rows x 128 cols, direct float4
            int rowb = f >> 5, cq = f & 31;
            *(float4*)&Bs[rowb][cq << 2] =
                *(const float4*)(W + (size_t)(kb + rowb) * 256 + n0 + (cq << 2));
        }
        __syncthreads();
#pragma unroll
        for (int k = 0; k < 32; ++k) {
            float a[8], b[8];
            *(float4*)&a[0] = *(const float4*)&As[k][tr];
            *(float4*)&a[4] = *(const float4*)&As[k][tr + 4];
            *(float4*)&b[0] = *(const float4*)&Bs[k][tc];
            *(float4*)&b[4] = *(const float4*)&Bs[k][tc + 4];
#pragma unroll
            for (int i = 0; i < 8; ++i)
#pragma unroll
                for (int j = 0; j < 8; ++j)
                    acc[i][j] = fmaf(a[i], b[j], acc[i][j]);
        }
        __syncthreads();
    }
#pragma unroll
    for (int i = 0; i < 8; ++i) {
        float* yp = Y + (size_t)(m0 + tr + i) * 256 + n0 + tc;
        *(float4*)yp = make_float4(acc[i][0], acc[i][1], acc[i][2], acc[i][3]);
        *(float4*)(yp + 4) = make_float4(acc[i][4], acc[i][5], acc[i][6], acc[i][7]);
    }
}

// ---------------------------------------------------------------------------
// Kernel B: the sequential scan. One wave64 per batch sample; lane owns
// neurons 4*lane .. 4*lane+3. Spikes shared wave-wide via __ballot (no LDS,
// no barriers). z@w_rec done sparsely (z is binary & rare).
// i_x aliases the zs output region: read-before-overwrite per (t,b,n).
// ---------------------------------------------------------------------------
__global__ __launch_bounds__(64) void lif_seq(const float* __restrict__ ix,
                                              const float* __restrict__ wrec,
                                              const float* __restrict__ z0,
                                              const float* __restrict__ v0,
                                              const float* __restrict__ t0,
                                              float* __restrict__ zs,
                                              float* __restrict__ vs,
                                              int T, int B) {
    const int b = blockIdx.x;
    const int lane = threadIdx.x;
    const int nbase = lane << 2;
    const size_t sb = (size_t)b * 256 + nbase;
    const size_t stride = (size_t)B * 256;

    float4 v = *(const float4*)(v0 + sb);
    float4 tt = *(const float4*)(t0 + sb);
    float4 z = *(const float4*)(z0 + sb);

    unsigned long long mask0 = __ballot(z.x != 0.f);
    unsigned long long mask1 = __ballot(z.y != 0.f);
    unsigned long long mask2 = __ballot(z.z != 0.f);
    unsigned long long mask3 = __ballot(z.w != 0.f);

    const float* ixp = ix + sb;

    auto step = [&](int t, float4 ixv) {
        // sparse z @ w_rec
        float ir[4] = {0.f, 0.f, 0.f, 0.f};
#pragma unroll
        for (int k = 0; k < 4; ++k) {
            unsigned long long m = (k == 0) ? mask0 : (k == 1) ? mask1 : (k == 2) ? mask2 : mask3;
            while (m) {
                int j = __builtin_ctzll(m);
                m &= m - 1;
                const float4 w = *(const float4*)(wrec + ((size_t)((j << 2) + k) << 8) + nbase);
                ir[0] += w.x; ir[1] += w.y; ir[2] += w.z; ir[3] += w.w;
            }
        }
        float iv[4] = {ixv.x, ixv.y, ixv.z, ixv.w};
        float vv[4] = {v.x, v.y, v.z, v.w};
        float tv[4] = {tt.x, tt.y, tt.z, tt.w};
        float zv[4] = {z.x, z.y, z.z, z.w};
        float nz[4];
#pragma unroll
        for (int c = 0; c < 4; ++c) {
            float i_in = iv[c] + ir[c];
            float h = (i_in != 0.f) ? 1.f : 0.f;
            float nt = tv[c] + (1.f - h);
            float nv = vv[c] * (1.f - zv[c]);
            float lp = (nv > -1.f) ? 1.f : 0.f;
            nv = nv - (1.f - lp) * (nv + 1.f);
            float cap = exp2f(fabsf(nv)) - 1.f;                 // A=B=C=1
            float arg = fminf(h * (nt + 1.f), cap);             // DT=1
            float sgn = (nv > 0.f) ? 1.f : ((nv < 0.f) ? -1.f : 0.f);
            nv = nv - sgn * log2f((1e-5f + arg) + 1.f);
            nv = nv + i_in;
            nt = nt * (1.f - h);
            vv[c] = nv;
            tv[c] = nt;
            nz[c] = ((nv - 0.5f) > 0.f) ? 1.f : 0.f;            // spike fwd: (v-THR)/THR > 0
        }
        v = make_float4(vv[0], vv[1], vv[2], vv[3]);
        tt = make_float4(tv[0], tv[1], tv[2], tv[3]);
        z = make_float4(nz[0], nz[1], nz[2], nz[3]);
        mask0 = __ballot(nz[0] != 0.f);
        mask1 = __ballot(nz[1] != 0.f);
        mask2 = __ballot(nz[2] != 0.f);
        mask3 = __ballot(nz[3] != 0.f);
        size_t o = (size_t)t * stride + sb;
        *(float4*)(zs + o) = z;   // overwrites ix[t,b,*] AFTER it was consumed
        *(float4*)(vs + o) = v;
    };

    // 8-deep register prefetch, all indices static (unrolled)
    float4 buf[8];
#pragma unroll
    for (int u = 0; u < 8; ++u) buf[u] = *(const float4*)(ixp + (size_t)u * stride);

    for (int tb = 0; tb < T; tb += 8) {
#pragma unroll
        for (int u = 0; u < 8; ++u) {
            step(tb + u, buf[u]);
            int tn = tb + u + 8;
            tn = (tn < T) ? tn : (T - 1);   // clamped dummy loads at tail (unused)
            buf[u] = *(const float4*)(ixp + (size_t)tn * stride);
        }
    }
}

extern "C" void kernel_launch(void* const* d_in, const int* in_sizes, int n_in,
                              void* d_out, int out_size, void* d_ws, size_t ws_size,
                              hipStream_t stream) {
    const float* x    = (const float*)d_in[0];
    const float* z0   = (const float*)d_in[1];
    const float* v0   = (const float*)d_in[2];
    const float* t0   = (const float*)d_in[3];
    const float* w_in = (const float*)d_in[4];
    const float* wrec = (const float*)d_in[5];

    const int n_rec = 256;
    const int B = in_sizes[1] / n_rec;          // 128
    const int nin = in_sizes[4] / n_rec;        // 256
    const int T = in_sizes[0] / (B * nin);      // 1000
    const int M = T * B;                        // 128000

    float* zs = (float*)d_out;
    float* vs = zs + (size_t)T * B * n_rec;
    float* ixbuf = zs;  // stage x@w_in into the zs region (read-before-write in lif_seq)

    gemm_xw<<<dim3((M / 128) * 2), dim3(256), 0, stream>>>(x, w_in, ixbuf, M);
    lif_seq<<<dim3(B), dim3(64), 0, stream>>>(ixbuf, wrec, z0, v0, t0, zs, vs, T, B);
}

// Round 2
// 536.311 us; speedup vs baseline: 1.2139x; 1.2139x over previous
//
#include <hip/hip_runtime.h>

// ---------------------------------------------------------------------------
// Kernel A: i_x[t,b,n] = sum_k x[t,b,k] * w_in[k,n]
// Plain fp32 vector GEMM: M = T*B = 128000, K = 256, N = 256.
// Tile 128x128, 256 threads, 8x8 micro-tile per thread, BK=32.  (~112 TF)
// ---------------------------------------------------------------------------
__global__ __launch_bounds__(256) void gemm_xw(const float* __restrict__ X,
                                               const float* __restrict__ W,
                                               float* __restrict__ Y,
                                               int M) {
    __shared__ float As[32][132];
    __shared__ float Bs[32][128];

    const int tid = threadIdx.x;
    const int mb = blockIdx.x >> 1;
    const int nb = blockIdx.x & 1;
    const int m0 = mb << 7;
    const int n0 = nb << 7;
    const int tr = (tid >> 4) << 3;
    const int tc = (tid & 15) << 3;

    float acc[8][8];
#pragma unroll
    for (int i = 0; i < 8; ++i)
#pragma unroll
        for (int j = 0; j < 8; ++j) acc[i][j] = 0.f;

    for (int kb = 0; kb < 256; kb += 32) {
#pragma unroll
        for (int i = 0; i < 4; ++i) {
            int f = tid + (i << 8);
            int row = f >> 3, kq = f & 7;
            float4 a = *(const float4*)(X + (size_t)(m0 + row) * 256 + kb + (kq << 2));
            As[(kq << 2) + 0][row] = a.x;
            As[(kq << 2) + 1][row] = a.y;
            As[(kq << 2) + 2][row] = a.z;
            As[(kq << 2) + 3][row] = a.w;
            int rowb = f >> 5, cq = f & 31;
            *(float4*)&Bs[rowb][cq << 2] =
                *(const float4*)(W + (size_t)(kb + rowb) * 256 + n0 + (cq << 2));
        }
        __syncthreads();
#pragma unroll
        for (int k = 0; k < 32; ++k) {
            float a[8], b[8];
            *(float4*)&a[0] = *(const float4*)&As[k][tr];
            *(float4*)&a[4] = *(const float4*)&As[k][tr + 4];
            *(float4*)&b[0] = *(const float4*)&Bs[k][tc];
            *(float4*)&b[4] = *(const float4*)&Bs[k][tc + 4];
#pragma unroll
            for (int i = 0; i < 8; ++i)
#pragma unroll
                for (int j = 0; j < 8; ++j)
                    acc[i][j] = fmaf(a[i], b[j], acc[i][j]);
        }
        __syncthreads();
    }
#pragma unroll
    for (int i = 0; i < 8; ++i) {
        float* yp = Y + (size_t)(m0 + tr + i) * 256 + n0 + tc;
        *(float4*)yp = make_float4(acc[i][0], acc[i][1], acc[i][2], acc[i][3]);
        *(float4*)(yp + 4) = make_float4(acc[i][4], acc[i][5], acc[i][6], acc[i][7]);
    }
}

// ---------------------------------------------------------------------------
// Kernel B: sequential scan. One block (256 threads = 4 waves) per batch
// sample; lane owns exactly one neuron. Spike masks exchanged via ballot +
// double-buffered LDS slots + ONE barrier per step. z@w_rec done sparsely.
// i_x aliases the zs output region: read-before-overwrite per (t,b,n).
// ---------------------------------------------------------------------------
__global__ __launch_bounds__(256) void lif_seq(const float* __restrict__ ix,
                                               const float* __restrict__ wrec,
                                               const float* __restrict__ z0,
                                               const float* __restrict__ v0,
                                               const float* __restrict__ t0,
                                               float* __restrict__ zs,
                                               float* __restrict__ vs,
                                               int T, int B) {
    const int b = blockIdx.x;
    const int n = threadIdx.x;          // neuron index 0..255
    const int w = n >> 6;               // wave id 0..3
    const size_t sb = (size_t)b * 256 + n;
    const size_t stride = (size_t)B * 256;

    __shared__ unsigned long long smask[2][4];

    float v = v0[sb];
    float t = t0[sb];
    float z = z0[sb];

    // initial spike masks from z0
    {
        unsigned long long m = __ballot(z != 0.f);
        if ((n & 63) == 0) smask[0][w] = m;
    }
    __syncthreads();
    unsigned long long mk0 = smask[0][0];
    unsigned long long mk1 = smask[0][1];
    unsigned long long mk2 = smask[0][2];
    unsigned long long mk3 = smask[0][3];
    int p = 1;

    const float* ixp = ix + sb;

    auto step = [&](int ts, float r) {
        // sparse z @ w_rec : gather spiking rows (block-uniform masks)
        float ir = 0.f;
        unsigned long long mm;
        mm = mk0;
        while (mm) { int j = __builtin_ctzll(mm); mm &= mm - 1;
                     ir += wrec[((size_t)j << 8) + n]; }
        mm = mk1;
        while (mm) { int j = __builtin_ctzll(mm); mm &= mm - 1;
                     ir += wrec[((size_t)(64 + j) << 8) + n]; }
        mm = mk2;
        while (mm) { int j = __builtin_ctzll(mm); mm &= mm - 1;
                     ir += wrec[((size_t)(128 + j) << 8) + n]; }
        mm = mk3;
        while (mm) { int j = __builtin_ctzll(mm); mm &= mm - 1;
                     ir += wrec[((size_t)(192 + j) << 8) + n]; }

        float i_in = r + ir;
        float h = (i_in != 0.f) ? 1.f : 0.f;
        float nt = t + (1.f - h);
        float nv = (z != 0.f) ? 0.f : v;          // reset on spike (z in {0,1})
        nv = fmaxf(nv, -1.f);                     // exact clamp at -1
        float cap = __builtin_amdgcn_exp2f(fabsf(nv)) - 1.f;   // A=B=C=1
        float arg = fminf(h * (nt + 1.f), cap);                // DT=1
        float L = __builtin_amdgcn_logf((1e-5f + arg) + 1.f);  // log2
        float sgn = (nv > 0.f) ? 1.f : ((nv < 0.f) ? -1.f : 0.f);
        nv = fmaf(-sgn, L, nv);                   // exact: sgn in {-1,0,1}
        nv = nv + i_in;
        nt = nt * (1.f - h);
        float nz = ((nv - 0.5f) > 0.f) ? 1.f : 0.f;  // spike fwd, THR=0.5

        v = nv; t = nt; z = nz;

        unsigned long long mw = __ballot(nz != 0.f);
        if ((n & 63) == 0) smask[p][w] = mw;
        __syncthreads();
        mk0 = smask[p][0];
        mk1 = smask[p][1];
        mk2 = smask[p][2];
        mk3 = smask[p][3];
        p ^= 1;

        size_t o = (size_t)ts * stride + sb;
        zs[o] = nz;     // overwrites ix[ts,b,n] AFTER it was consumed
        vs[o] = nv;
    };

    // 8-deep register prefetch of the i_x stream, static indices only
    float buf[8];
#pragma unroll
    for (int u = 0; u < 8; ++u) buf[u] = ixp[(size_t)u * stride];

    for (int tb = 0; tb < T; tb += 8) {
#pragma unroll
        for (int u = 0; u < 8; ++u) {
            step(tb + u, buf[u]);
            int tn = tb + u + 8;
            tn = (tn < T) ? tn : (T - 1);    // clamped dummy loads at tail
            buf[u] = ixp[(size_t)tn * stride];
        }
    }
}

extern "C" void kernel_launch(void* const* d_in, const int* in_sizes, int n_in,
                              void* d_out, int out_size, void* d_ws, size_t ws_size,
                              hipStream_t stream) {
    const float* x    = (const float*)d_in[0];
    const float* z0   = (const float*)d_in[1];
    const float* v0   = (const float*)d_in[2];
    const float* t0   = (const float*)d_in[3];
    const float* w_in = (const float*)d_in[4];
    const float* wrec = (const float*)d_in[5];

    const int n_rec = 256;
    const int B = in_sizes[1] / n_rec;          // 128
    const int nin = in_sizes[4] / n_rec;        // 256
    const int T = in_sizes[0] / (B * nin);      // 1000
    const int M = T * B;                        // 128000

    float* zs = (float*)d_out;
    float* vs = zs + (size_t)T * B * n_rec;
    float* ixbuf = zs;  // stage x@w_in into the zs region (read-before-write in lif_seq)

    gemm_xw<<<dim3((M / 128) * 2), dim3(256), 0, stream>>>(x, w_in, ixbuf, M);
    lif_seq<<<dim3(B), dim3(256), 0, stream>>>(ixbuf, wrec, z0, v0, t0, zs, vs, T, B);
}